// Round 1
// baseline (2812.134 us; speedup 1.0000x reference)
//
#include <hip/hip_runtime.h>
#include <math.h>

#define C 40

// ---------------- mask dtype detection ----------------
// flags bit0: words not all in {0,1}  (so NOT int32 0/1)
// flags bit1: words not all in {0, 0x3F800000} (so NOT float 0.0/1.0)
__global__ void k_detect(const unsigned int* __restrict__ w, int nwords,
                         unsigned int* __restrict__ flags) {
    int i = blockIdx.x * blockDim.x + threadIdx.x;
    unsigned int viol = 0;
    for (; i < nwords; i += gridDim.x * blockDim.x) {
        unsigned int v = w[i];
        if (!(v == 0u || v == 1u)) viol |= 1u;
        if (!(v == 0u || v == 0x3F800000u)) viol |= 2u;
    }
    if (viol) atomicOr(flags, viol);
}

__device__ __forceinline__ bool read_mask(const void* mp, unsigned int fl, int n) {
    if ((fl & 1u) == 0u) return ((const int*)mp)[n] != 0;        // int32 {0,1}
    if ((fl & 2u) == 0u) return ((const float*)mp)[n] != 0.0f;   // float {0,1}
    return ((const unsigned char*)mp)[n] != 0;                   // bool bytes
}

// ---------------- degree / norm ----------------
__global__ void k_deg(const int* __restrict__ dst, int* __restrict__ deg, int E) {
    int i = blockIdx.x * blockDim.x + threadIdx.x;
    if (i < E) atomicAdd(&deg[dst[i]], 1);
}

__global__ void k_dinv(const int* __restrict__ deg, float* __restrict__ dinv, int n) {
    int i = blockIdx.x * blockDim.x + threadIdx.x;
    if (i < n) {
        int d = deg[i];
        dinv[i] = (d > 0) ? rsqrtf((float)d) : 0.0f;
    }
}

// ---------------- exclusive scan (3-phase) over deg -> rowptr ----------------
__global__ void k_scan1(const int* __restrict__ deg, int* __restrict__ rowptr,
                        int* __restrict__ bsum, int n) {
    __shared__ int sm[256];
    int tid = threadIdx.x;
    int i = blockIdx.x * 256 + tid;
    int v = (i < n) ? deg[i] : 0;
    sm[tid] = v;
    __syncthreads();
#pragma unroll
    for (int o = 1; o < 256; o <<= 1) {
        int t = (tid >= o) ? sm[tid - o] : 0;
        __syncthreads();
        sm[tid] += t;
        __syncthreads();
    }
    if (i <= n) rowptr[i] = sm[tid] - v;  // exclusive
    if (tid == 255) bsum[blockIdx.x] = sm[255];
}

__global__ void k_scan2(int* __restrict__ bsum, int nb) {
    __shared__ int sm[512];
    int tid = threadIdx.x;
    int v = (tid < nb) ? bsum[tid] : 0;
    sm[tid] = v;
    __syncthreads();
    for (int o = 1; o < 512; o <<= 1) {
        int t = (tid >= o) ? sm[tid - o] : 0;
        __syncthreads();
        sm[tid] += t;
        __syncthreads();
    }
    if (tid < nb) bsum[tid] = sm[tid] - v;  // exclusive over block sums
}

__global__ void k_scan3(int* __restrict__ rowptr, const int* __restrict__ bsum, int n) {
    int i = blockIdx.x * 256 + threadIdx.x;
    if (i <= n) rowptr[i] += bsum[blockIdx.x];
}

// ---------------- CSR scatter: pk[pos] = {src, norm} ----------------
__global__ void k_csr(const int* __restrict__ src, const int* __restrict__ dst,
                      const float* __restrict__ dinv, const int* __restrict__ rowptr,
                      int* __restrict__ fill, int2* __restrict__ pk, int E) {
    int e = blockIdx.x * blockDim.x + threadIdx.x;
    if (e < E) {
        int s = src[e], d = dst[e];
        int pos = rowptr[d] + atomicAdd(&fill[d], 1);
        pk[pos] = make_int2(s, __float_as_int(dinv[s] * dinv[d]));
    }
}

// ---------------- error = mask ? onehot - y_soft : 0 ; sigma pieces ----------------
__global__ void k_error(const float* __restrict__ y_soft, const int* __restrict__ y_true,
                        const void* __restrict__ maskp, const unsigned int* __restrict__ flags,
                        float* __restrict__ err, float* __restrict__ s_sig,
                        float* __restrict__ s_cnt, int total) {
    int i = blockIdx.x * blockDim.x + threadIdx.x;
    unsigned int fl = *flags;
    float a = 0.f, cnt = 0.f;
    if (i < total) {
        int n = i / C;
        int c = i - n * C;
        bool m = read_mask(maskp, fl, n);
        float e = 0.f;
        if (m) {
            e = ((c == y_true[n]) ? 1.0f : 0.0f) - y_soft[i];
            if (c == 0) cnt = 1.0f;
        }
        err[i] = e;
        a = fabsf(e);
    }
    __shared__ float sA[256];
    __shared__ float sC[256];
    int tid = threadIdx.x;
    sA[tid] = a; sC[tid] = cnt;
    __syncthreads();
    for (int o = 128; o; o >>= 1) {
        if (tid < o) { sA[tid] += sA[tid + o]; sC[tid] += sC[tid + o]; }
        __syncthreads();
    }
    if (tid == 0) {
        if (sA[0] != 0.f) atomicAdd(s_sig, sA[0]);
        if (sC[0] != 0.f) atomicAdd(s_cnt, sC[0]);
    }
}

// ---------------- propagation layer: one wave per dst node ----------------
// POST=0: clip(-1,1);  POST=1: softmax over classes
template <int POST>
__global__ __launch_bounds__(256) void k_prop(
    const int* __restrict__ rowptr, const int2* __restrict__ pk,
    const float* __restrict__ x, const float* __restrict__ y0,
    float* __restrict__ out, float alpha, float beta, int n) {
    int wid = (blockIdx.x * blockDim.x + threadIdx.x) >> 6;
    int lane = threadIdx.x & 63;
    if (wid >= n) return;
    int beg = rowptr[wid], end = rowptr[wid + 1];
    float acc0 = 0.f, acc1 = 0.f, acc2 = 0.f, acc3 = 0.f;
    float v = 0.f;
    if (lane < C) {
        int e = beg;
        for (; e + 4 <= end; e += 4) {
            int2 p0 = pk[e], p1 = pk[e + 1], p2 = pk[e + 2], p3 = pk[e + 3];
            acc0 = fmaf(__int_as_float(p0.y), x[p0.x * C + lane], acc0);
            acc1 = fmaf(__int_as_float(p1.y), x[p1.x * C + lane], acc1);
            acc2 = fmaf(__int_as_float(p2.y), x[p2.x * C + lane], acc2);
            acc3 = fmaf(__int_as_float(p3.y), x[p3.x * C + lane], acc3);
        }
        for (; e < end; ++e) {
            int2 p = pk[e];
            acc0 = fmaf(__int_as_float(p.y), x[p.x * C + lane], acc0);
        }
        float acc = (acc0 + acc1) + (acc2 + acc3);
        v = fmaf(alpha, acc, beta * y0[wid * C + lane]);
    }
    if (POST == 0) {
        if (lane < C) out[wid * C + lane] = fminf(1.0f, fmaxf(-1.0f, v));
    } else {
        float mx = (lane < C) ? v : -3.0e38f;
#pragma unroll
        for (int o = 32; o; o >>= 1) mx = fmaxf(mx, __shfl_xor(mx, o));
        float ex = (lane < C) ? __expf(v - mx) : 0.0f;
        float s = ex;
#pragma unroll
        for (int o = 32; o; o >>= 1) s += __shfl_xor(s, o);
        if (lane < C) out[wid * C + lane] = ex / s;
    }
}

// ---------------- scale + y0 build: one wave per node ----------------
__global__ __launch_bounds__(256) void k_scale(
    const float* __restrict__ sm_err, const float* __restrict__ y_soft,
    const int* __restrict__ y_true, const void* __restrict__ maskp,
    const unsigned int* __restrict__ flags, const float* __restrict__ s_sig,
    const float* __restrict__ s_cnt, float* __restrict__ y0, int n) {
    int wid = (blockIdx.x * blockDim.x + threadIdx.x) >> 6;
    int lane = threadIdx.x & 63;
    if (wid >= n) return;
    float v = 0.f, a = 0.f;
    if (lane < C) {
        v = sm_err[wid * C + lane];
        a = fabsf(v);
    }
#pragma unroll
    for (int o = 32; o; o >>= 1) a += __shfl_xor(a, o);
    float sigma = (*s_sig) / (*s_cnt);
    float scale = sigma / a;
    if (isinf(scale) || scale > 1000.0f) scale = 1.0f;
    if (lane < C) {
        bool m = read_mask(maskp, *flags, wid);
        float yc = fmaf(scale, v, y_soft[wid * C + lane]);
        y0[wid * C + lane] = m ? ((lane == y_true[wid]) ? 1.0f : 0.0f) : yc;
    }
}

extern "C" void kernel_launch(void* const* d_in, const int* in_sizes, int n_in,
                              void* d_out, int out_size, void* d_ws, size_t ws_size,
                              hipStream_t stream) {
    const int* y_true = (const int*)d_in[0];
    const float* y_soft = (const float*)d_in[1];
    const void* maskp = d_in[2];
    const int* ei = (const int*)d_in[3];
    const int n = in_sizes[0];
    const int total = in_sizes[1];          // n * C
    const int E = in_sizes[3] / 2;
    const int* src = ei;
    const int* dst = ei + E;

    char* ws = (char*)d_ws;
    size_t off = 0;
    auto alloc = [&](size_t bytes) -> char* {
        char* p = ws + off;
        off += (bytes + 63) & ~(size_t)63;
        return p;
    };
    int* deg = (int*)alloc((size_t)n * 4);
    int* fill = (int*)alloc((size_t)n * 4);
    float* s_sig = (float*)alloc(4);
    float* s_cnt = (float*)alloc(4);
    unsigned int* flags = (unsigned int*)alloc(4);
    size_t zero_bytes = off;                 // zero everything above each call
    float* dinv = (float*)alloc((size_t)n * 4);
    int* rowptr = (int*)alloc((size_t)(n + 1) * 4);
    int* bsum = (int*)alloc(4096);
    int2* pk = (int2*)alloc((size_t)E * 8);
    float* bufA = (float*)alloc((size_t)total * 4);
    float* bufE = (float*)alloc((size_t)total * 4);
    (void)ws_size;

    hipMemsetAsync(d_ws, 0, zero_bytes, stream);

    k_detect<<<98, 256, 0, stream>>>((const unsigned int*)maskp, n / 4, flags);
    k_deg<<<(E + 255) / 256, 256, 0, stream>>>(dst, deg, E);
    k_dinv<<<(n + 255) / 256, 256, 0, stream>>>(deg, dinv, n);

    int nb1 = (n + 1 + 255) / 256;
    k_scan1<<<nb1, 256, 0, stream>>>(deg, rowptr, bsum, n);
    k_scan2<<<1, 512, 0, stream>>>(bsum, nb1);
    k_scan3<<<nb1, 256, 0, stream>>>(rowptr, bsum, n);
    k_csr<<<(E + 255) / 256, 256, 0, stream>>>(src, dst, dinv, rowptr, fill, pk, E);

    k_error<<<(total + 255) / 256, 256, 0, stream>>>(y_soft, y_true, maskp, flags,
                                                     bufE, s_sig, s_cnt, total);

    const int pb = (n + 3) / 4;  // 4 waves per 256-thread block, 1 node per wave
    const float A1 = 0.979f, B1 = (float)(1.0 - 0.979);
    const float A2 = 0.756f, B2 = (float)(1.0 - 0.756);
    float* bufs[2] = { bufA, (float*)d_out };

    // correct phase: 10 layers, post = clip
    const float* x = bufE;
    for (int it = 0; it < 10; ++it) {
        k_prop<0><<<pb, 256, 0, stream>>>(rowptr, pk, x, bufE, bufs[it & 1], A1, B1, n);
        x = bufs[it & 1];
    }
    // x == d_out holds smoothed_error; build y0 into bufE
    k_scale<<<pb, 256, 0, stream>>>(x, y_soft, y_true, maskp, flags, s_sig, s_cnt, bufE, n);

    // smooth phase: 10 layers, post = softmax; final layer lands in d_out
    x = bufE;
    for (int it = 0; it < 10; ++it) {
        k_prop<1><<<pb, 256, 0, stream>>>(rowptr, pk, x, bufE, bufs[it & 1], A2, B2, n);
        x = bufs[it & 1];
    }
}

// Round 2
// 2472.435 us; speedup vs baseline: 1.1374x; 1.1374x over previous
//
#include <hip/hip_runtime.h>
#include <math.h>

#define C 40

// ---------------- mask dtype detection ----------------
// flags bit0: words not all in {0,1}  (so NOT int32 0/1)
// flags bit1: words not all in {0, 0x3F800000} (so NOT float 0.0/1.0)
__global__ void k_detect(const unsigned int* __restrict__ w, int nwords,
                         unsigned int* __restrict__ flags) {
    int i = blockIdx.x * blockDim.x + threadIdx.x;
    unsigned int viol = 0;
    for (; i < nwords; i += gridDim.x * blockDim.x) {
        unsigned int v = w[i];
        if (!(v == 0u || v == 1u)) viol |= 1u;
        if (!(v == 0u || v == 0x3F800000u)) viol |= 2u;
    }
    if (viol) atomicOr(flags, viol);
}

__device__ __forceinline__ bool read_mask(const void* mp, unsigned int fl, int n) {
    if ((fl & 1u) == 0u) return ((const int*)mp)[n] != 0;        // int32 {0,1}
    if ((fl & 2u) == 0u) return ((const float*)mp)[n] != 0.0f;   // float {0,1}
    return ((const unsigned char*)mp)[n] != 0;                   // bool bytes
}

// ---------------- degree / norm ----------------
__global__ void k_deg(const int* __restrict__ dst, int* __restrict__ deg, int E) {
    int i = blockIdx.x * blockDim.x + threadIdx.x;
    if (i < E) atomicAdd(&deg[dst[i]], 1);
}

__global__ void k_dinv(const int* __restrict__ deg, float* __restrict__ dinv, int n) {
    int i = blockIdx.x * blockDim.x + threadIdx.x;
    if (i < n) {
        int d = deg[i];
        dinv[i] = (d > 0) ? rsqrtf((float)d) : 0.0f;
    }
}

// ---------------- exclusive scan (3-phase) over deg -> rowptr ----------------
__global__ void k_scan1(const int* __restrict__ deg, int* __restrict__ rowptr,
                        int* __restrict__ bsum, int n) {
    __shared__ int sm[256];
    int tid = threadIdx.x;
    int i = blockIdx.x * 256 + tid;
    int v = (i < n) ? deg[i] : 0;
    sm[tid] = v;
    __syncthreads();
#pragma unroll
    for (int o = 1; o < 256; o <<= 1) {
        int t = (tid >= o) ? sm[tid - o] : 0;
        __syncthreads();
        sm[tid] += t;
        __syncthreads();
    }
    if (i <= n) rowptr[i] = sm[tid] - v;  // exclusive
    if (tid == 255) bsum[blockIdx.x] = sm[255];
}

__global__ void k_scan2(int* __restrict__ bsum, int nb) {
    __shared__ int sm[512];
    int tid = threadIdx.x;
    int v = (tid < nb) ? bsum[tid] : 0;
    sm[tid] = v;
    __syncthreads();
    for (int o = 1; o < 512; o <<= 1) {
        int t = (tid >= o) ? sm[tid - o] : 0;
        __syncthreads();
        sm[tid] += t;
        __syncthreads();
    }
    if (tid < nb) bsum[tid] = sm[tid] - v;  // exclusive over block sums
}

__global__ void k_scan3(int* __restrict__ rowptr, const int* __restrict__ bsum, int n) {
    int i = blockIdx.x * 256 + threadIdx.x;
    if (i <= n) rowptr[i] += bsum[blockIdx.x];
}

// ---------------- CSR scatter: pk[pos] = {src, norm} ----------------
__global__ void k_csr(const int* __restrict__ src, const int* __restrict__ dst,
                      const float* __restrict__ dinv, const int* __restrict__ rowptr,
                      int* __restrict__ fill, int2* __restrict__ pk, int E) {
    int e = blockIdx.x * blockDim.x + threadIdx.x;
    if (e < E) {
        int s = src[e], d = dst[e];
        int pos = rowptr[d] + atomicAdd(&fill[d], 1);
        pk[pos] = make_int2(s, __float_as_int(dinv[s] * dinv[d]));
    }
}

// ---------------- error = mask ? onehot - y_soft : 0 ; block partials ----------------
// one thread per float4 (4 classes); fixed 2048-block grid-stride; NO global atomics.
__global__ __launch_bounds__(256) void k_error(
    const float4* __restrict__ ys4, const int* __restrict__ y_true,
    const void* __restrict__ maskp, const unsigned int* __restrict__ flags,
    float4* __restrict__ err4, float* __restrict__ psig, float* __restrict__ pcnt,
    int nquads) {
    unsigned int fl = *flags;
    float a = 0.f, cnt = 0.f;
    for (int i = blockIdx.x * blockDim.x + threadIdx.x; i < nquads;
         i += gridDim.x * blockDim.x) {
        int node = i / 10;        // C/4 = 10 quads per node (magic-div)
        int q = i - node * 10;
        float4 e = make_float4(0.f, 0.f, 0.f, 0.f);
        if (read_mask(maskp, fl, node)) {
            int yt = y_true[node];
            float4 ys = ys4[i];
            int c0 = q * 4;
            e.x = ((c0 + 0) == yt ? 1.f : 0.f) - ys.x;
            e.y = ((c0 + 1) == yt ? 1.f : 0.f) - ys.y;
            e.z = ((c0 + 2) == yt ? 1.f : 0.f) - ys.z;
            e.w = ((c0 + 3) == yt ? 1.f : 0.f) - ys.w;
            a += fabsf(e.x) + fabsf(e.y) + fabsf(e.z) + fabsf(e.w);
            if (q == 0) cnt += 1.f;
        }
        err4[i] = e;
    }
    __shared__ float sA[256];
    __shared__ float sC[256];
    int tid = threadIdx.x;
    sA[tid] = a; sC[tid] = cnt;
    __syncthreads();
    for (int o = 128; o; o >>= 1) {
        if (tid < o) { sA[tid] += sA[tid + o]; sC[tid] += sC[tid + o]; }
        __syncthreads();
    }
    if (tid == 0) { psig[blockIdx.x] = sA[0]; pcnt[blockIdx.x] = sC[0]; }
}

__global__ __launch_bounds__(256) void k_reduce(
    const float* __restrict__ psig, const float* __restrict__ pcnt,
    float* __restrict__ s_sig, float* __restrict__ s_cnt, int nb) {
    float a = 0.f, c = 0.f;
    for (int i = threadIdx.x; i < nb; i += 256) { a += psig[i]; c += pcnt[i]; }
    __shared__ float sA[256];
    __shared__ float sC[256];
    int tid = threadIdx.x;
    sA[tid] = a; sC[tid] = c;
    __syncthreads();
    for (int o = 128; o; o >>= 1) {
        if (tid < o) { sA[tid] += sA[tid + o]; sC[tid] += sC[tid + o]; }
        __syncthreads();
    }
    if (tid == 0) { *s_sig = sA[0]; *s_cnt = sC[0]; }
}

// ---------------- propagation layer: one wave per dst node ----------------
// POST=0: clip(-1,1);  POST=1: softmax over classes
template <int POST>
__global__ __launch_bounds__(256) void k_prop(
    const int* __restrict__ rowptr, const int2* __restrict__ pk,
    const float* __restrict__ x, const float* __restrict__ y0,
    float* __restrict__ out, float alpha, float beta, int n) {
    int wid = (blockIdx.x * blockDim.x + threadIdx.x) >> 6;
    int lane = threadIdx.x & 63;
    if (wid >= n) return;
    int beg = rowptr[wid], end = rowptr[wid + 1];
    float acc0 = 0.f, acc1 = 0.f, acc2 = 0.f, acc3 = 0.f;
    float v = 0.f;
    if (lane < C) {
        int e = beg;
        for (; e + 8 <= end; e += 8) {
            int2 p0 = pk[e], p1 = pk[e + 1], p2 = pk[e + 2], p3 = pk[e + 3];
            int2 p4 = pk[e + 4], p5 = pk[e + 5], p6 = pk[e + 6], p7 = pk[e + 7];
            float x0 = x[p0.x * C + lane];
            float x1 = x[p1.x * C + lane];
            float x2 = x[p2.x * C + lane];
            float x3 = x[p3.x * C + lane];
            float x4 = x[p4.x * C + lane];
            float x5 = x[p5.x * C + lane];
            float x6 = x[p6.x * C + lane];
            float x7 = x[p7.x * C + lane];
            acc0 = fmaf(__int_as_float(p0.y), x0, acc0);
            acc1 = fmaf(__int_as_float(p1.y), x1, acc1);
            acc2 = fmaf(__int_as_float(p2.y), x2, acc2);
            acc3 = fmaf(__int_as_float(p3.y), x3, acc3);
            acc0 = fmaf(__int_as_float(p4.y), x4, acc0);
            acc1 = fmaf(__int_as_float(p5.y), x5, acc1);
            acc2 = fmaf(__int_as_float(p6.y), x6, acc2);
            acc3 = fmaf(__int_as_float(p7.y), x7, acc3);
        }
        for (; e < end; ++e) {
            int2 p = pk[e];
            acc0 = fmaf(__int_as_float(p.y), x[p.x * C + lane], acc0);
        }
        float acc = (acc0 + acc1) + (acc2 + acc3);
        v = fmaf(alpha, acc, beta * y0[wid * C + lane]);
    }
    if (POST == 0) {
        if (lane < C) out[wid * C + lane] = fminf(1.0f, fmaxf(-1.0f, v));
    } else {
        float mx = (lane < C) ? v : -3.0e38f;
#pragma unroll
        for (int o = 32; o; o >>= 1) mx = fmaxf(mx, __shfl_xor(mx, o));
        float ex = (lane < C) ? __expf(v - mx) : 0.0f;
        float s = ex;
#pragma unroll
        for (int o = 32; o; o >>= 1) s += __shfl_xor(s, o);
        if (lane < C) out[wid * C + lane] = ex / s;
    }
}

// ---------------- scale + y0 build: one wave per node ----------------
__global__ __launch_bounds__(256) void k_scale(
    const float* __restrict__ sm_err, const float* __restrict__ y_soft,
    const int* __restrict__ y_true, const void* __restrict__ maskp,
    const unsigned int* __restrict__ flags, const float* __restrict__ s_sig,
    const float* __restrict__ s_cnt, float* __restrict__ y0, int n) {
    int wid = (blockIdx.x * blockDim.x + threadIdx.x) >> 6;
    int lane = threadIdx.x & 63;
    if (wid >= n) return;
    float v = 0.f, a = 0.f;
    if (lane < C) {
        v = sm_err[wid * C + lane];
        a = fabsf(v);
    }
#pragma unroll
    for (int o = 32; o; o >>= 1) a += __shfl_xor(a, o);
    float sigma = (*s_sig) / (*s_cnt);
    float scale = sigma / a;
    if (isinf(scale) || scale > 1000.0f) scale = 1.0f;
    if (lane < C) {
        bool m = read_mask(maskp, *flags, wid);
        float yc = fmaf(scale, v, y_soft[wid * C + lane]);
        y0[wid * C + lane] = m ? ((lane == y_true[wid]) ? 1.0f : 0.0f) : yc;
    }
}

extern "C" void kernel_launch(void* const* d_in, const int* in_sizes, int n_in,
                              void* d_out, int out_size, void* d_ws, size_t ws_size,
                              hipStream_t stream) {
    const int* y_true = (const int*)d_in[0];
    const float* y_soft = (const float*)d_in[1];
    const void* maskp = d_in[2];
    const int* ei = (const int*)d_in[3];
    const int n = in_sizes[0];
    const int total = in_sizes[1];          // n * C
    const int E = in_sizes[3] / 2;
    const int* src = ei;
    const int* dst = ei + E;

    char* ws = (char*)d_ws;
    size_t off = 0;
    auto alloc = [&](size_t bytes) -> char* {
        char* p = ws + off;
        off += (bytes + 63) & ~(size_t)63;
        return p;
    };
    int* deg = (int*)alloc((size_t)n * 4);
    int* fill = (int*)alloc((size_t)n * 4);
    unsigned int* flags = (unsigned int*)alloc(4);
    size_t zero_bytes = off;                 // zero everything above each call
    float* s_sig = (float*)alloc(4);
    float* s_cnt = (float*)alloc(4);
    float* psig = (float*)alloc(2048 * 4);
    float* pcnt = (float*)alloc(2048 * 4);
    float* dinv = (float*)alloc((size_t)n * 4);
    int* rowptr = (int*)alloc((size_t)(n + 1) * 4);
    int* bsum = (int*)alloc(4096);
    int2* pk = (int2*)alloc((size_t)E * 8);
    float* bufA = (float*)alloc((size_t)total * 4);
    float* bufE = (float*)alloc((size_t)total * 4);
    (void)ws_size;

    hipMemsetAsync(d_ws, 0, zero_bytes, stream);

    k_detect<<<98, 256, 0, stream>>>((const unsigned int*)maskp, n / 4, flags);
    k_deg<<<(E + 255) / 256, 256, 0, stream>>>(dst, deg, E);
    k_dinv<<<(n + 255) / 256, 256, 0, stream>>>(deg, dinv, n);

    int nb1 = (n + 1 + 255) / 256;
    k_scan1<<<nb1, 256, 0, stream>>>(deg, rowptr, bsum, n);
    k_scan2<<<1, 512, 0, stream>>>(bsum, nb1);
    k_scan3<<<nb1, 256, 0, stream>>>(rowptr, bsum, n);
    k_csr<<<(E + 255) / 256, 256, 0, stream>>>(src, dst, dinv, rowptr, fill, pk, E);

    k_error<<<2048, 256, 0, stream>>>((const float4*)y_soft, y_true, maskp, flags,
                                      (float4*)bufE, psig, pcnt, total / 4);
    k_reduce<<<1, 256, 0, stream>>>(psig, pcnt, s_sig, s_cnt, 2048);

    const int pb = (n + 3) / 4;  // 4 waves per 256-thread block, 1 node per wave
    const float A1 = 0.979f, B1 = (float)(1.0 - 0.979);
    const float A2 = 0.756f, B2 = (float)(1.0 - 0.756);
    float* bufs[2] = { bufA, (float*)d_out };

    // correct phase: 10 layers, post = clip
    const float* x = bufE;
    for (int it = 0; it < 10; ++it) {
        k_prop<0><<<pb, 256, 0, stream>>>(rowptr, pk, x, bufE, bufs[it & 1], A1, B1, n);
        x = bufs[it & 1];
    }
    // x == d_out holds smoothed_error; build y0 into bufE
    k_scale<<<pb, 256, 0, stream>>>(x, y_soft, y_true, maskp, flags, s_sig, s_cnt, bufE, n);

    // smooth phase: 10 layers, post = softmax; final layer lands in d_out
    x = bufE;
    for (int it = 0; it < 10; ++it) {
        k_prop<1><<<pb, 256, 0, stream>>>(rowptr, pk, x, bufE, bufs[it & 1], A2, B2, n);
        x = bufs[it & 1];
    }
}